// Round 17
// baseline (285.315 us; speedup 1.0000x reference)
//
#include <hip/hip_runtime.h>
#include <hip/hip_bf16.h>
#include <hip/hip_fp8.h>
#include <math.h>

#define NIN 128
#define HC 128
#define NOUT 768
#define KVSTRIDE 384   // bytes per kv row: 128 B fp8 k | 256 B bf16 v

typedef __attribute__((ext_vector_type(8))) short bf16x8;
typedef __attribute__((ext_vector_type(4))) float f32x4;
typedef __attribute__((ext_vector_type(4))) unsigned short ushort4v;
typedef __attribute__((ext_vector_type(8))) unsigned short ushort8v;

__device__ __forceinline__ unsigned short f2bf(float f) {
    __hip_bfloat16 h = __float2bfloat16(f);
    return *(unsigned short*)&h;
}

__device__ __forceinline__ float bfe(ushort8v u, int j) {
    return __uint_as_float(((unsigned int)u[j]) << 16);
}

__device__ __forceinline__ float f8tof(unsigned char b) {
    __hip_fp8_e4m3 h; h.__x = b; return (float)h;
}
__device__ __forceinline__ unsigned char ftof8(float f) {
    __hip_fp8_e4m3 h(f); return h.__x;
}

// ---------------- Dispatch 1: prep_w (blocks 0..3) + hist (blocks 4..) ----------------
__global__ __launch_bounds__(256) void prep_hist(
    const float* __restrict__ Wq, const float* __restrict__ Wk,
    const float* __restrict__ Wv, const float* __restrict__ Wsk,
    unsigned short* __restrict__ Wtb,
    const int* __restrict__ ei, int* __restrict__ cnt, int E)
{
    if (blockIdx.x < 4) {
        const float* W = (blockIdx.x == 0) ? Wq : (blockIdx.x == 1) ? Wk
                       : (blockIdx.x == 2) ? Wv : Wsk;
        unsigned short* out = Wtb + (size_t)blockIdx.x * 128 * 128;
        const int t = threadIdx.x;
        for (int s = 0; s < 16; ++s) {
            const int f = t + s * 256;
            const int k = f >> 5;
            const int n = (f & 31) * 4;
            float4 w4 = *(const float4*)(W + (size_t)k * 128 + n);
            out[(size_t)(n    ) * 128 + k] = f2bf(w4.x);
            out[(size_t)(n + 1) * 128 + k] = f2bf(w4.y);
            out[(size_t)(n + 2) * 128 + k] = f2bf(w4.z);
            out[(size_t)(n + 3) * 128 + k] = f2bf(w4.w);
        }
    } else {
        const int e = (blockIdx.x - 4) * 256 + threadIdx.x;
        if (e < E) atomicAdd(cnt + ei[E + e], 1);
    }
}

// ---------------- scan ----------------
__global__ __launch_bounds__(1024) void scan_part(
    const int* __restrict__ cnt, int* __restrict__ start,
    int* __restrict__ bsum, int N)
{
    __shared__ int wsum[16];
    const int tid = threadIdx.x;
    const int lane = tid & 63;
    const int w = tid >> 6;
    const int i = blockIdx.x * 1024 + tid;
    const int v = (i < N) ? cnt[i] : 0;
    int xv = v;
    #pragma unroll
    for (int off = 1; off < 64; off <<= 1) {
        const int y = __shfl_up(xv, off, 64);
        if (lane >= off) xv += y;
    }
    if (lane == 63) wsum[w] = xv;
    __syncthreads();
    if (tid < 16) {
        int y = wsum[tid];
        #pragma unroll
        for (int off = 1; off < 16; off <<= 1) {
            const int z = __shfl_up(y, off, 64);
            if (tid >= off) y += z;
        }
        wsum[tid] = y;
    }
    __syncthreads();
    const int excl = (w > 0 ? wsum[w - 1] : 0) + xv - v;
    if (i < N) start[i] = excl;
    if (tid == 1023) bsum[blockIdx.x] = wsum[15];
}

// add chunk prefix + build 64-bin degree histogram (LDS-aggregated)
__global__ __launch_bounds__(256) void scan_add(
    int* __restrict__ start, int* __restrict__ cursor,
    const int* __restrict__ bsum, const int* __restrict__ cnt,
    int* __restrict__ bins, int N, int NB)
{
    __shared__ int pref;
    __shared__ int lbins[64];
    const int i = blockIdx.x * 256 + threadIdx.x;
    const int chunk = (blockIdx.x * 256) >> 10;
    if (threadIdx.x < 64) lbins[threadIdx.x] = 0;
    if (threadIdx.x == 0) {
        int s = 0;
        for (int b = 0; b < chunk; ++b) s += bsum[b];
        pref = s;
    }
    __syncthreads();
    if (i < N) {
        const int s = start[i] + pref;
        start[i] = s;
        cursor[i] = s;
        atomicAdd(&lbins[min(cnt[i], 63)], 1);
    }
    __syncthreads();
    if (threadIdx.x < 64 && lbins[threadIdx.x])
        atomicAdd(bins + threadIdx.x, lbins[threadIdx.x]);
}

// 1-wave exclusive scan of 64 degree bins -> bucket cursors
__global__ __launch_bounds__(64) void bucket_scan(
    const int* __restrict__ bins, int* __restrict__ bcur)
{
    const int t = threadIdx.x;
    const int v = bins[t];
    int xv = v;
    #pragma unroll
    for (int off = 1; off < 64; off <<= 1) {
        const int y = __shfl_up(xv, off, 64);
        if (t >= off) xv += y;
    }
    bcur[t] = xv - v;
}

// ---------------- Dispatch 5: gemm_kv + csr scatter + degree-sort scatter ----------------
__global__ __launch_bounds__(256, 4) void gemm_scatter(
    const float* __restrict__ x, const unsigned short* __restrict__ Wtb,
    const float* __restrict__ bk, const float* __restrict__ bv,
    unsigned char* __restrict__ kvb, int N,
    const int* __restrict__ ei, int* __restrict__ cursor,
    int* __restrict__ csr_src, int E, int nGemm, int nScat,
    const int* __restrict__ cnt, int* __restrict__ bcur, int* __restrict__ perm)
{
    __shared__ unsigned short At[128][136];

    if ((int)blockIdx.x >= nGemm + nScat) {
        // degree-sort scatter (block-aggregated bucket reservation)
        __shared__ int lh[64], lbase[64];
        const int idx = (blockIdx.x - nGemm - nScat) * 256 + threadIdx.x;
        if (threadIdx.x < 64) lh[threadIdx.x] = 0;
        __syncthreads();
        int d = 0, slot = 0;
        if (idx < N) {
            d = min(cnt[idx], 63);
            slot = atomicAdd(&lh[d], 1);
        }
        __syncthreads();
        if (threadIdx.x < 64 && lh[threadIdx.x])
            lbase[threadIdx.x] = atomicAdd(bcur + threadIdx.x, lh[threadIdx.x]);
        __syncthreads();
        if (idx < N) perm[lbase[d] + slot] = idx;
        return;
    }

    if ((int)blockIdx.x >= nGemm) {
        const int e = (blockIdx.x - nGemm) * 256 + threadIdx.x;
        if (e < E) {
            const int d = ei[E + e];
            const int pos = atomicAdd(cursor + d, 1);
            csr_src[pos] = ei[e];
        }
        return;
    }

    const int tid = threadIdx.x;
    const int lane = tid & 63;
    const int wave = tid >> 6;
    const int rowBase = blockIdx.x * 128;
    const bool full = (rowBase + 128 <= N);

    #pragma unroll
    for (int s = 0; s < 16; ++s) {
        const int f = tid + s * 256;
        const int r = f >> 5;
        const int cl = (f & 31) * 4;
        const int gr = rowBase + r;
        float4 a4 = make_float4(0.f, 0.f, 0.f, 0.f);
        if (full || gr < N) a4 = *(const float4*)(x + (size_t)gr * 128 + cl);
        ushort4v u;
        u.x = f2bf(a4.x); u.y = f2bf(a4.y); u.z = f2bf(a4.z); u.w = f2bf(a4.w);
        *(ushort4v*)&At[r][cl] = u;
    }
    __syncthreads();

    bf16x8 afr[2][4];
    #pragma unroll
    for (int m = 0; m < 2; ++m)
        #pragma unroll
        for (int kk = 0; kk < 4; ++kk)
            afr[m][kk] = *(bf16x8*)&At[wave * 32 + m * 16 + (lane & 15)]
                                    [kk * 32 + (lane >> 4) * 8];

    const int colb = lane & 15;
    const int kofs = (lane >> 4) * 8;
    const int g4   = (lane >> 4) * 4;

    #pragma unroll
    for (int w2 = 0; w2 < 2; ++w2) {
        const unsigned short* Wp = Wtb + (size_t)(1 + w2) * 128 * 128;  // Wk, Wv
        const float* bias = (w2 == 0) ? bk : bv;

        f32x4 acc[2][8];
        #pragma unroll
        for (int m = 0; m < 2; ++m)
            #pragma unroll
            for (int nr = 0; nr < 8; ++nr)
                acc[m][nr] = (f32x4){0.f, 0.f, 0.f, 0.f};

        #pragma unroll
        for (int nr = 0; nr < 8; ++nr) {
            bf16x8 bfr[4];
            #pragma unroll
            for (int kk = 0; kk < 4; ++kk)
                bfr[kk] = *(const bf16x8*)(Wp + (size_t)(nr * 16 + colb) * 128
                                               + kk * 32 + kofs);
            #pragma unroll
            for (int kk = 0; kk < 4; ++kk) {
                #pragma unroll
                for (int m = 0; m < 2; ++m)
                    acc[m][nr] = __builtin_amdgcn_mfma_f32_16x16x32_bf16(
                        bfr[kk], afr[m][kk], acc[m][nr], 0, 0, 0);   // swapped
            }
        }

        #pragma unroll
        for (int m = 0; m < 2; ++m) {
            const int xrow = rowBase + wave * 32 + m * 16 + (lane & 15);
            if (full || xrow < N) {
                unsigned char* row = kvb + (size_t)xrow * KVSTRIDE;
                #pragma unroll
                for (int nr = 0; nr < 8; ++nr) {
                    const int colb4 = nr * 16 + g4;
                    const float4 b4 = *(const float4*)(bias + colb4);
                    if (w2 == 0) {   // k -> fp8, 4 B per lane
                        unsigned int p = (unsigned int)ftof8(acc[m][nr][0] + b4.x)
                                       | ((unsigned int)ftof8(acc[m][nr][1] + b4.y) << 8)
                                       | ((unsigned int)ftof8(acc[m][nr][2] + b4.z) << 16)
                                       | ((unsigned int)ftof8(acc[m][nr][3] + b4.w) << 24);
                        *(unsigned int*)(row + colb4) = p;
                    } else {         // v -> bf16, 8 B per lane
                        ushort4v pk;
                        pk.x = f2bf(acc[m][nr][0] + b4.x);
                        pk.y = f2bf(acc[m][nr][1] + b4.y);
                        pk.z = f2bf(acc[m][nr][2] + b4.z);
                        pk.w = f2bf(acc[m][nr][3] + b4.w);
                        *(ushort4v*)(row + 128 + 2 * colb4) = pk;
                    }
                }
            }
        }
    }
}

// ---------------- Kernel B: fused q/skip-MFMA + attention + gate ----------------
// 512 threads, 32 nodes/block taken from the DEGREE-SORTED perm (equal-degree
// nodes share a wave -> minimal masked iterations). Depth-1 rolling prefetch
// pinned with sched_barrier.
__global__ __launch_bounds__(512, 4) void node_aggr_fused(
    const float* __restrict__ x, const unsigned short* __restrict__ Wtb,
    const float* __restrict__ bq, const float* __restrict__ bsk,
    const unsigned char* __restrict__ kvb,
    const int* __restrict__ start, const int* __restrict__ cnt,
    const int* __restrict__ csr_src, const float* __restrict__ Wbeta,
    const int* __restrict__ perm,
    __hip_bfloat16* __restrict__ gout, int N)
{
    __shared__ unsigned short At[32][136];
    __shared__ unsigned short q_l[32][136];
    __shared__ unsigned short sk_l[32][136];

    const int tid = threadIdx.x;
    const int lane = tid & 63;
    const int wave = tid >> 6;        // 0..7
    const int n0 = blockIdx.x * 32;

    const int g  = lane >> 4;
    const int t  = lane & 15;
    const int ch = t * 8;
    const int r  = wave * 4 + g;      // 0..31
    const int n  = n0 + r;
    const bool nok = (n < N);
    const int pn = nok ? perm[n] : 0;
    int s0v = 0, cntv = 0;
    if (nok) { s0v = start[pn]; cntv = cnt[pn]; }

    // stage x rows of the 32 permuted nodes -> bf16 LDS
    #pragma unroll
    for (int s = 0; s < 2; ++s) {
        const int f = tid + s * 512;
        const int rr = f >> 5;
        const int cl = (f & 31) * 4;
        const int gn = n0 + rr;
        float4 a4 = make_float4(0.f, 0.f, 0.f, 0.f);
        if (gn < N) {
            const int ps = perm[gn];
            a4 = *(const float4*)(x + (size_t)ps * 128 + cl);
        }
        ushort4v u;
        u.x = f2bf(a4.x); u.y = f2bf(a4.y); u.z = f2bf(a4.z); u.w = f2bf(a4.w);
        *(ushort4v*)&At[rr][cl] = u;
    }
    __syncthreads();

    // phase 1: q & skip MFMA. Wave w: row-half mh=w>>2 (16 rows), col-pair (w&3)*2.
    {
        const int mh = wave >> 2;
        bf16x8 afr[4];
        #pragma unroll
        for (int kk = 0; kk < 4; ++kk)
            afr[kk] = *(bf16x8*)&At[mh * 16 + (lane & 15)][kk * 32 + (lane >> 4) * 8];
        const int colb = lane & 15;
        const int kofs = (lane >> 4) * 8;
        const int g4m  = (lane >> 4) * 4;
        const int rm   = mh * 16 + (lane & 15);

        f32x4 acc[2][2];
        #pragma unroll
        for (int a = 0; a < 2; ++a)
            #pragma unroll
            for (int b = 0; b < 2; ++b)
                acc[a][b] = (f32x4){0.f, 0.f, 0.f, 0.f};

        #pragma unroll
        for (int nr2 = 0; nr2 < 2; ++nr2) {
            const int nr = (wave & 3) * 2 + nr2;
            #pragma unroll
            for (int wsel = 0; wsel < 2; ++wsel) {
                const unsigned short* Wp = Wtb + (size_t)(wsel == 0 ? 0 : 3) * 128 * 128;
                bf16x8 bfr[4];
                #pragma unroll
                for (int kk = 0; kk < 4; ++kk)
                    bfr[kk] = *(const bf16x8*)(Wp + (size_t)(nr * 16 + colb) * 128
                                                   + kk * 32 + kofs);
                #pragma unroll
                for (int kk = 0; kk < 4; ++kk)
                    acc[wsel][nr2] = __builtin_amdgcn_mfma_f32_16x16x32_bf16(
                        bfr[kk], afr[kk], acc[wsel][nr2], 0, 0, 0);
            }
        }

        #pragma unroll
        for (int nr2 = 0; nr2 < 2; ++nr2) {
            const int col = ((wave & 3) * 2 + nr2) * 16 + g4m;
            ushort4v qp, sp;
            #pragma unroll
            for (int j = 0; j < 4; ++j) {
                qp[j] = f2bf(acc[0][nr2][j] + bq[col + j]);
                sp[j] = f2bf(acc[1][nr2][j] + bsk[col + j]);
            }
            *(ushort4v*)&q_l[rm][col]  = qp;
            *(ushort4v*)&sk_l[rm][col] = sp;
        }
    }
    __syncthreads();

    // ---- phase 2: group-per-node, 2-edge pipeline + pinned depth-1 prefetch ----
    const float scale = 0.17677669529663687f;   // 1/sqrt(32)

    float qv[8];
    {
        const ushort8v q8 = *(const ushort8v*)&q_l[r][ch];
        #pragma unroll
        for (int j = 0; j < 8; ++j) qv[j] = bfe(q8, j);
    }

    const int e1v = s0v + cntv;
    float den = 0.f;
    float acc[8];
    #pragma unroll
    for (int j = 0; j < 8; ++j) acc[j] = 0.f;

    for (int base = s0v; base < e1v; base += 16) {
        const int nblk = min(16, e1v - base);
        const int sidx = csr_src[base + min(t, nblk - 1)];
        int sa = __shfl(sidx, g * 16, 64);
        int sb = __shfl(sidx, g * 16 + min(1, nblk - 1), 64);
        const unsigned char* rowa = kvb + (size_t)sa * KVSTRIDE;
        const unsigned char* rowb = kvb + (size_t)sb * KVSTRIDE;
        uint2 ka = *(const uint2*)(rowa + ch);
        ushort8v va = *(const ushort8v*)(rowa + 128 + 2 * ch);
        uint2 kb = *(const uint2*)(rowb + ch);
        ushort8v vb = *(const ushort8v*)(rowb + 128 + 2 * ch);
        int j = 0;
        for (; j + 1 < nblk; j += 2) {
            const int sna = __shfl(sidx, g * 16 + min(j + 2, nblk - 1), 64);
            const int snb = __shfl(sidx, g * 16 + min(j + 3, nblk - 1), 64);
            const unsigned char* rna = kvb + (size_t)sna * KVSTRIDE;
            const unsigned char* rnb = kvb + (size_t)snb * KVSTRIDE;
            const uint2 kna = *(const uint2*)(rna + ch);
            const ushort8v vna = *(const ushort8v*)(rna + 128 + 2 * ch);
            const uint2 knb = *(const uint2*)(rnb + ch);
            const ushort8v vnb = *(const ushort8v*)(rnb + 128 + 2 * ch);
            __builtin_amdgcn_sched_barrier(0);   // pin prefetch issue above compute
            float pa = 0.f, pb = 0.f;
            #pragma unroll
            for (int jj = 0; jj < 4; ++jj) {
                pa = fmaf(f8tof((ka.x >> (8 * jj)) & 0xff), qv[jj], pa);
                pa = fmaf(f8tof((ka.y >> (8 * jj)) & 0xff), qv[4 + jj], pa);
                pb = fmaf(f8tof((kb.x >> (8 * jj)) & 0xff), qv[jj], pb);
                pb = fmaf(f8tof((kb.y >> (8 * jj)) & 0xff), qv[4 + jj], pb);
            }
            pa += __shfl_xor(pa, 1, 64);
            pa += __shfl_xor(pa, 2, 64);
            pb += __shfl_xor(pb, 1, 64);
            pb += __shfl_xor(pb, 2, 64);
            const float exa = __expf(pa * scale);
            const float exb = __expf(pb * scale);
            den += exa + exb;
            #pragma unroll
            for (int jj = 0; jj < 8; ++jj)
                acc[jj] = fmaf(bfe(va, jj), exa, fmaf(bfe(vb, jj), exb, acc[jj]));
            ka = kna; va = vna; kb = knb; vb = vnb;
        }
        if (j < nblk) {
            float pa = 0.f;
            #pragma unroll
            for (int jj = 0; jj < 4; ++jj) {
                pa = fmaf(f8tof((ka.x >> (8 * jj)) & 0xff), qv[jj], pa);
                pa = fmaf(f8tof((ka.y >> (8 * jj)) & 0xff), qv[4 + jj], pa);
            }
            pa += __shfl_xor(pa, 1, 64);
            pa += __shfl_xor(pa, 2, 64);
            const float exa = __expf(pa * scale);
            den += exa;
            #pragma unroll
            for (int jj = 0; jj < 8; ++jj) acc[jj] = fmaf(bfe(va, jj), exa, acc[jj]);
        }
    }

    // epilogue — group-local
    const float inv = 1.f / (den + 1e-16f);
    float o[8], sk[8];
    {
        const ushort8v s8 = *(const ushort8v*)&sk_l[r][ch];
        #pragma unroll
        for (int j = 0; j < 8; ++j) sk[j] = bfe(s8, j);
    }
    float part = 0.f;
    #pragma unroll
    for (int j = 0; j < 8; ++j) {
        o[j] = acc[j] * inv;
        part += o[j] * Wbeta[ch + j] + sk[j] * Wbeta[HC + ch + j]
              + (o[j] - sk[j]) * Wbeta[2 * HC + ch + j];
    }
    part += __shfl_xor(part, 1, 64);
    part += __shfl_xor(part, 2, 64);
    part += __shfl_xor(part, 4, 64);
    part += __shfl_xor(part, 8, 64);

    const float beta = 1.f / (1.f + __expf(-part));
    if (nok) {
        union { unsigned short h[8]; ushort8v v8; } pk;
        #pragma unroll
        for (int j = 0; j < 8; ++j) {
            float rv = beta * sk[j] + (1.f - beta) * o[j];
            rv = (rv >= 0.f) ? rv : 0.01f * rv;
            pk.h[j] = f2bf(rv);
        }
        *(ushort8v*)(gout + (size_t)pn * HC + ch) = pk.v8;
    }
}

// ---------------- fused pool + final GEMM (4 graphs per block) ----------------
__global__ __launch_bounds__(256) void pool_final(
    const __hip_bfloat16* __restrict__ gout, const int* __restrict__ batch,
    const float* __restrict__ W2, const float* __restrict__ b2,
    float* __restrict__ out, int N, int G)
{
    const int g0 = blockIdx.x * 4;
    __shared__ float p[4][HC];
    const int wave = threadIdx.x >> 6;
    const int lane = threadIdx.x & 63;
    const int g = g0 + wave;
    if (g < G) {
        int lo = 0, hi = N;
        while (lo < hi) { const int m = (lo + hi) >> 1; if (batch[m] < g) lo = m + 1; else hi = m; }
        int lo2 = lo, hi2 = N;
        while (lo2 < hi2) { const int m = (lo2 + hi2) >> 1; if (batch[m] < g + 1) lo2 = m + 1; else hi2 = m; }
        float a0 = 0.f, a1 = 0.f;
        for (int r = lo; r < lo2; ++r) {
            const __hip_bfloat162 g2 = *(const __hip_bfloat162*)(gout + (size_t)r * HC + 2 * lane);
            a0 += __bfloat162float(g2.x);
            a1 += __bfloat162float(g2.y);
        }
        const float invc = 1.f / fmaxf((float)(lo2 - lo), 1.f);
        p[wave][2 * lane]     = a0 * invc;
        p[wave][2 * lane + 1] = a1 * invc;
    }
    __syncthreads();
    const int t = threadIdx.x;
    for (int j = t; j < NOUT; j += 256) {
        const float bj = b2[j];
        float a0 = bj, a1 = bj, a2 = bj, a3 = bj;
        #pragma unroll 4
        for (int c = 0; c < HC; ++c) {
            const float w = W2[(size_t)c * NOUT + j];
            a0 = fmaf(p[0][c], w, a0);
            a1 = fmaf(p[1][c], w, a1);
            a2 = fmaf(p[2][c], w, a2);
            a3 = fmaf(p[3][c], w, a3);
        }
        if (g0     < G) out[(size_t)(g0    ) * NOUT + j] = a0;
        if (g0 + 1 < G) out[(size_t)(g0 + 1) * NOUT + j] = a1;
        if (g0 + 2 < G) out[(size_t)(g0 + 2) * NOUT + j] = a2;
        if (g0 + 3 < G) out[(size_t)(g0 + 3) * NOUT + j] = a3;
    }
}

// ---------------- launch ----------------
extern "C" void kernel_launch(void* const* d_in, const int* in_sizes, int n_in,
                              void* d_out, int out_size, void* d_ws, size_t ws_size,
                              hipStream_t stream) {
    const float* x     = (const float*)d_in[0];
    const int*   ei    = (const int*)d_in[1];
    const int*   batch = (const int*)d_in[2];
    const float* Wq  = (const float*)d_in[3];  const float* bq  = (const float*)d_in[4];
    const float* Wk  = (const float*)d_in[5];  const float* bk  = (const float*)d_in[6];
    const float* Wv  = (const float*)d_in[7];  const float* bv  = (const float*)d_in[8];
    const float* Wsk = (const float*)d_in[9];  const float* bsk = (const float*)d_in[10];
    const float* Wbeta = (const float*)d_in[11];
    const float* W2  = (const float*)d_in[12]; const float* b2  = (const float*)d_in[13];

    const int N = in_sizes[0] / NIN;
    const int E = in_sizes[1] / 2;
    const int G = out_size / NOUT;

    char* ws = (char*)d_ws;
    unsigned char* kvb = (unsigned char*)ws;                  // N x 384 B
    char* p0 = ws + (size_t)N * KVSTRIDE;
    unsigned short* Wtb = (unsigned short*)p0;            p0 += 4 * 128 * 128 * sizeof(unsigned short);
    int* cnt    = (int*)p0;                               p0 += (size_t)N * sizeof(int);
    int* bins   = (int*)p0;                               p0 += 64 * sizeof(int);
    int* bcur   = (int*)p0;                               p0 += 64 * sizeof(int);
    int* start  = (int*)p0;                               p0 += (size_t)N * sizeof(int);
    int* cursor = (int*)p0;                               p0 += (size_t)N * sizeof(int);
    int* bsum   = (int*)p0;                               p0 += 1024 * sizeof(int);
    int* csr    = (int*)p0;                               p0 += (size_t)E * sizeof(int);
    int* perm   = (int*)p0;                               p0 += (size_t)N * sizeof(int);
    __hip_bfloat16* gout = (__hip_bfloat16*)p0;

    // zero cnt + bins (contiguous)
    hipMemsetAsync(cnt, 0, ((size_t)N + 64) * sizeof(int), stream);

    const int eb = (E + 255) / 256;
    const int NB = (N + 1023) / 1024;
    const int nGemm = (N + 127) / 128;
    const int nPerm = (N + 255) / 256;

    prep_hist<<<4 + eb, 256, 0, stream>>>(Wq, Wk, Wv, Wsk, Wtb, ei, cnt, E);
    scan_part<<<NB, 1024, 0, stream>>>(cnt, start, bsum, N);
    scan_add<<<(N + 255) / 256, 256, 0, stream>>>(start, cursor, bsum, cnt, bins, N, NB);
    bucket_scan<<<1, 64, 0, stream>>>(bins, bcur);
    gemm_scatter<<<nGemm + eb + nPerm, 256, 0, stream>>>(x, Wtb, bk, bv, kvb, N,
                                                         ei, cursor, csr, E,
                                                         nGemm, eb, cnt, bcur, perm);

    node_aggr_fused<<<(N + 31) / 32, 512, 0, stream>>>(x, Wtb, bq, bsk, kvb,
                                                       start, cnt, csr, Wbeta,
                                                       perm, gout, N);

    pool_final<<<(G + 3) / 4, 256, 0, stream>>>(gout, batch, W2, b2,
                                                (float*)d_out, N, G);
}

// Round 18
// 262.171 us; speedup vs baseline: 1.0883x; 1.0883x over previous
//
#include <hip/hip_runtime.h>
#include <hip/hip_bf16.h>
#include <hip/hip_fp8.h>
#include <math.h>

#define NIN 128
#define HC 128
#define NOUT 768
#define KVSTRIDE 384   // bytes per kv row: 128 B fp8 k | 256 B bf16 v

typedef __attribute__((ext_vector_type(8))) short bf16x8;
typedef __attribute__((ext_vector_type(4))) float f32x4;
typedef __attribute__((ext_vector_type(4))) unsigned short ushort4v;
typedef __attribute__((ext_vector_type(8))) unsigned short ushort8v;

__device__ __forceinline__ unsigned short f2bf(float f) {
    __hip_bfloat16 h = __float2bfloat16(f);
    return *(unsigned short*)&h;
}

__device__ __forceinline__ float bfe(ushort8v u, int j) {
    return __uint_as_float(((unsigned int)u[j]) << 16);
}

__device__ __forceinline__ float f8tof(unsigned char b) {
    __hip_fp8_e4m3 h; h.__x = b; return (float)h;
}
__device__ __forceinline__ unsigned char ftof8(float f) {
    __hip_fp8_e4m3 h(f); return h.__x;
}

// ---------------- Dispatch 1: prep_w (blocks 0..3) + hist (blocks 4..) ----------------
__global__ __launch_bounds__(256) void prep_hist(
    const float* __restrict__ Wq, const float* __restrict__ Wk,
    const float* __restrict__ Wv, const float* __restrict__ Wsk,
    unsigned short* __restrict__ Wtb,
    const int* __restrict__ ei, int* __restrict__ cnt, int E)
{
    if (blockIdx.x < 4) {
        const float* W = (blockIdx.x == 0) ? Wq : (blockIdx.x == 1) ? Wk
                       : (blockIdx.x == 2) ? Wv : Wsk;
        unsigned short* out = Wtb + (size_t)blockIdx.x * 128 * 128;
        const int t = threadIdx.x;
        for (int s = 0; s < 16; ++s) {
            const int f = t + s * 256;
            const int k = f >> 5;
            const int n = (f & 31) * 4;
            float4 w4 = *(const float4*)(W + (size_t)k * 128 + n);
            out[(size_t)(n    ) * 128 + k] = f2bf(w4.x);
            out[(size_t)(n + 1) * 128 + k] = f2bf(w4.y);
            out[(size_t)(n + 2) * 128 + k] = f2bf(w4.z);
            out[(size_t)(n + 3) * 128 + k] = f2bf(w4.w);
        }
    } else {
        const int e = (blockIdx.x - 4) * 256 + threadIdx.x;
        if (e < E) atomicAdd(cnt + ei[E + e], 1);
    }
}

// ---------------- scan: per-1024-chunk local exclusive offsets ----------------
__global__ __launch_bounds__(1024) void scan_part(
    const int* __restrict__ cnt, int* __restrict__ start,
    int* __restrict__ cursor, int* __restrict__ bsum, int N)
{
    __shared__ int wsum[16];
    const int tid = threadIdx.x;
    const int lane = tid & 63;
    const int w = tid >> 6;
    const int i = blockIdx.x * 1024 + tid;
    const int v = (i < N) ? cnt[i] : 0;
    int xv = v;
    #pragma unroll
    for (int off = 1; off < 64; off <<= 1) {
        const int y = __shfl_up(xv, off, 64);
        if (lane >= off) xv += y;
    }
    if (lane == 63) wsum[w] = xv;
    __syncthreads();
    if (tid < 16) {
        int y = wsum[tid];
        #pragma unroll
        for (int off = 1; off < 16; off <<= 1) {
            const int z = __shfl_up(y, off, 64);
            if (tid >= off) y += z;
        }
        wsum[tid] = y;
    }
    __syncthreads();
    const int excl = (w > 0 ? wsum[w - 1] : 0) + xv - v;
    if (i < N) { start[i] = excl; cursor[i] = excl; }
    if (tid == 1023) bsum[blockIdx.x] = wsum[15];
}

// 1-block exclusive scan of chunk totals (NB <= 128)
__global__ __launch_bounds__(128) void bpref_scan(
    const int* __restrict__ bsum, int* __restrict__ bpref, int NB)
{
    const int tid = threadIdx.x;
    __shared__ int w0tot;
    const int v = (tid < NB) ? bsum[tid] : 0;
    int xv = v;
    const int lane = tid & 63;
    #pragma unroll
    for (int off = 1; off < 64; off <<= 1) {
        const int y = __shfl_up(xv, off, 64);
        if (lane >= off) xv += y;
    }
    if (tid == 63) w0tot = xv;
    __syncthreads();
    const int incl = xv + ((tid >= 64) ? w0tot : 0);
    if (tid < NB) bpref[tid] = incl - v;
}

// ---------------- Dispatch 4: gemm_kv (blocks 0..nG-1) + scatter (rest) ----------------
__global__ __launch_bounds__(256, 4) void gemm_scatter(
    const float* __restrict__ x, const unsigned short* __restrict__ Wtb,
    const float* __restrict__ bk, const float* __restrict__ bv,
    unsigned char* __restrict__ kvb, int N,
    const int* __restrict__ ei, int* __restrict__ cursor,
    const int* __restrict__ bpref, int* __restrict__ csr_src, int E, int nGemm)
{
    __shared__ unsigned short At[128][136];

    if ((int)blockIdx.x >= nGemm) {
        const int e = (blockIdx.x - nGemm) * 256 + threadIdx.x;
        if (e < E) {
            const int d = ei[E + e];
            const int pos = bpref[d >> 10] + atomicAdd(cursor + d, 1);
            csr_src[pos] = ei[e];
        }
        return;
    }

    const int tid = threadIdx.x;
    const int lane = tid & 63;
    const int wave = tid >> 6;
    const int rowBase = blockIdx.x * 128;
    const bool full = (rowBase + 128 <= N);

    #pragma unroll
    for (int s = 0; s < 16; ++s) {
        const int f = tid + s * 256;
        const int r = f >> 5;
        const int cl = (f & 31) * 4;
        const int gr = rowBase + r;
        float4 a4 = make_float4(0.f, 0.f, 0.f, 0.f);
        if (full || gr < N) a4 = *(const float4*)(x + (size_t)gr * 128 + cl);
        ushort4v u;
        u.x = f2bf(a4.x); u.y = f2bf(a4.y); u.z = f2bf(a4.z); u.w = f2bf(a4.w);
        *(ushort4v*)&At[r][cl] = u;
    }
    __syncthreads();

    bf16x8 afr[2][4];
    #pragma unroll
    for (int m = 0; m < 2; ++m)
        #pragma unroll
        for (int kk = 0; kk < 4; ++kk)
            afr[m][kk] = *(bf16x8*)&At[wave * 32 + m * 16 + (lane & 15)]
                                    [kk * 32 + (lane >> 4) * 8];

    const int colb = lane & 15;
    const int kofs = (lane >> 4) * 8;
    const int g4   = (lane >> 4) * 4;

    #pragma unroll
    for (int w2 = 0; w2 < 2; ++w2) {
        const unsigned short* Wp = Wtb + (size_t)(1 + w2) * 128 * 128;  // Wk, Wv
        const float* bias = (w2 == 0) ? bk : bv;

        f32x4 acc[2][8];
        #pragma unroll
        for (int m = 0; m < 2; ++m)
            #pragma unroll
            for (int nr = 0; nr < 8; ++nr)
                acc[m][nr] = (f32x4){0.f, 0.f, 0.f, 0.f};

        #pragma unroll
        for (int nr = 0; nr < 8; ++nr) {
            bf16x8 bfr[4];
            #pragma unroll
            for (int kk = 0; kk < 4; ++kk)
                bfr[kk] = *(const bf16x8*)(Wp + (size_t)(nr * 16 + colb) * 128
                                               + kk * 32 + kofs);
            #pragma unroll
            for (int kk = 0; kk < 4; ++kk) {
                #pragma unroll
                for (int m = 0; m < 2; ++m)
                    acc[m][nr] = __builtin_amdgcn_mfma_f32_16x16x32_bf16(
                        bfr[kk], afr[m][kk], acc[m][nr], 0, 0, 0);   // swapped
            }
        }

        #pragma unroll
        for (int m = 0; m < 2; ++m) {
            const int xrow = rowBase + wave * 32 + m * 16 + (lane & 15);
            if (full || xrow < N) {
                unsigned char* row = kvb + (size_t)xrow * KVSTRIDE;
                #pragma unroll
                for (int nr = 0; nr < 8; ++nr) {
                    const int colb4 = nr * 16 + g4;
                    const float4 b4 = *(const float4*)(bias + colb4);
                    if (w2 == 0) {   // k -> fp8, 4 B per lane
                        unsigned int p = (unsigned int)ftof8(acc[m][nr][0] + b4.x)
                                       | ((unsigned int)ftof8(acc[m][nr][1] + b4.y) << 8)
                                       | ((unsigned int)ftof8(acc[m][nr][2] + b4.z) << 16)
                                       | ((unsigned int)ftof8(acc[m][nr][3] + b4.w) << 24);
                        *(unsigned int*)(row + colb4) = p;
                    } else {         // v -> bf16, 8 B per lane
                        ushort4v pk;
                        pk.x = f2bf(acc[m][nr][0] + b4.x);
                        pk.y = f2bf(acc[m][nr][1] + b4.y);
                        pk.z = f2bf(acc[m][nr][2] + b4.z);
                        pk.w = f2bf(acc[m][nr][3] + b4.w);
                        *(ushort4v*)(row + 128 + 2 * colb4) = pk;
                    }
                }
            }
        }
    }
}

// ---------------- Kernel B: fused q/skip-MFMA + attention + gate (R14 form) ----------------
__global__ __launch_bounds__(256) void node_aggr_fused(
    const float* __restrict__ x, const unsigned short* __restrict__ Wtb,
    const float* __restrict__ bq, const float* __restrict__ bsk,
    const unsigned char* __restrict__ kvb,
    const int* __restrict__ start, const int* __restrict__ cnt,
    const int* __restrict__ bpref,
    const int* __restrict__ csr_src, const float* __restrict__ Wbeta,
    __hip_bfloat16* __restrict__ gout, int N)
{
    __shared__ unsigned short At[16][136];
    __shared__ unsigned short q_l[16][136];
    __shared__ unsigned short sk_l[16][136];

    const int tid = threadIdx.x;
    const int lane = tid & 63;
    const int wave = tid >> 6;
    const int n0 = blockIdx.x * 16;

    const int g  = lane >> 4;
    const int t  = lane & 15;
    const int ch = t * 8;
    const int r  = wave * 4 + g;
    const int n  = n0 + r;
    const bool nok = (n < N);
    int s0v = 0, cntv = 0;
    if (nok) { s0v = start[n] + bpref[n >> 10]; cntv = cnt[n]; }

    #pragma unroll
    for (int s = 0; s < 2; ++s) {
        const int f = tid + s * 256;
        const int rr = f >> 5;
        const int cl = (f & 31) * 4;
        const int gr = n0 + rr;
        float4 a4 = make_float4(0.f, 0.f, 0.f, 0.f);
        if (gr < N) a4 = *(const float4*)(x + (size_t)gr * 128 + cl);
        ushort4v u;
        u.x = f2bf(a4.x); u.y = f2bf(a4.y); u.z = f2bf(a4.z); u.w = f2bf(a4.w);
        *(ushort4v*)&At[rr][cl] = u;
    }
    __syncthreads();

    {
        bf16x8 afr[4];
        #pragma unroll
        for (int kk = 0; kk < 4; ++kk)
            afr[kk] = *(bf16x8*)&At[lane & 15][kk * 32 + (lane >> 4) * 8];
        const int colb = lane & 15;
        const int kofs = (lane >> 4) * 8;
        const int g4m  = (lane >> 4) * 4;
        const int rm   = lane & 15;

        f32x4 acc[2][2];
        #pragma unroll
        for (int a = 0; a < 2; ++a)
            #pragma unroll
            for (int b = 0; b < 2; ++b)
                acc[a][b] = (f32x4){0.f, 0.f, 0.f, 0.f};

        #pragma unroll
        for (int nr2 = 0; nr2 < 2; ++nr2) {
            const int nr = wave * 2 + nr2;
            #pragma unroll
            for (int wsel = 0; wsel < 2; ++wsel) {
                const unsigned short* Wp = Wtb + (size_t)(wsel == 0 ? 0 : 3) * 128 * 128;
                bf16x8 bfr[4];
                #pragma unroll
                for (int kk = 0; kk < 4; ++kk)
                    bfr[kk] = *(const bf16x8*)(Wp + (size_t)(nr * 16 + colb) * 128
                                                   + kk * 32 + kofs);
                #pragma unroll
                for (int kk = 0; kk < 4; ++kk)
                    acc[wsel][nr2] = __builtin_amdgcn_mfma_f32_16x16x32_bf16(
                        bfr[kk], afr[kk], acc[wsel][nr2], 0, 0, 0);
            }
        }

        #pragma unroll
        for (int nr2 = 0; nr2 < 2; ++nr2) {
            const int col = (wave * 2 + nr2) * 16 + g4m;
            ushort4v qp, sp;
            #pragma unroll
            for (int j = 0; j < 4; ++j) {
                qp[j] = f2bf(acc[0][nr2][j] + bq[col + j]);
                sp[j] = f2bf(acc[1][nr2][j] + bsk[col + j]);
            }
            *(ushort4v*)&q_l[rm][col]  = qp;
            *(ushort4v*)&sk_l[rm][col] = sp;
        }
    }
    __syncthreads();

    // ---- phase 2: group-per-node, 2-edge pipeline, kv row [fp8 k | bf16 v] ----
    const float scale = 0.17677669529663687f;   // 1/sqrt(32)

    float qv[8];
    {
        const ushort8v q8 = *(const ushort8v*)&q_l[r][ch];
        #pragma unroll
        for (int j = 0; j < 8; ++j) qv[j] = bfe(q8, j);
    }

    const int e1v = s0v + cntv;
    float den = 0.f;
    float acc[8];
    #pragma unroll
    for (int j = 0; j < 8; ++j) acc[j] = 0.f;

    for (int base = s0v; base < e1v; base += 16) {
        const int nblk = min(16, e1v - base);
        const int sidx = csr_src[base + min(t, nblk - 1)];
        int j = 0;
        for (; j + 1 < nblk; j += 2) {
            const int sa = __shfl(sidx, g * 16 + j,     64);
            const int sb = __shfl(sidx, g * 16 + j + 1, 64);
            const unsigned char* rowa = kvb + (size_t)sa * KVSTRIDE;
            const unsigned char* rowb = kvb + (size_t)sb * KVSTRIDE;
            const uint2 k8a = *(const uint2*)(rowa + ch);          // 8 fp8
            const ushort8v v8a = *(const ushort8v*)(rowa + 128 + 2 * ch);
            const uint2 k8b = *(const uint2*)(rowb + ch);
            const ushort8v v8b = *(const ushort8v*)(rowb + 128 + 2 * ch);
            float pa = 0.f, pb = 0.f;
            #pragma unroll
            for (int jj = 0; jj < 4; ++jj) {
                pa = fmaf(f8tof((k8a.x >> (8 * jj)) & 0xff), qv[jj], pa);
                pa = fmaf(f8tof((k8a.y >> (8 * jj)) & 0xff), qv[4 + jj], pa);
                pb = fmaf(f8tof((k8b.x >> (8 * jj)) & 0xff), qv[jj], pb);
                pb = fmaf(f8tof((k8b.y >> (8 * jj)) & 0xff), qv[4 + jj], pb);
            }
            pa += __shfl_xor(pa, 1, 64);
            pa += __shfl_xor(pa, 2, 64);
            pb += __shfl_xor(pb, 1, 64);
            pb += __shfl_xor(pb, 2, 64);
            const float exa = __expf(pa * scale);
            const float exb = __expf(pb * scale);
            den += exa + exb;
            #pragma unroll
            for (int jj = 0; jj < 8; ++jj)
                acc[jj] = fmaf(bfe(v8a, jj), exa, fmaf(bfe(v8b, jj), exb, acc[jj]));
        }
        if (j < nblk) {
            const int sa = __shfl(sidx, g * 16 + j, 64);
            const unsigned char* rowa = kvb + (size_t)sa * KVSTRIDE;
            const uint2 k8a = *(const uint2*)(rowa + ch);
            const ushort8v v8a = *(const ushort8v*)(rowa + 128 + 2 * ch);
            float pa = 0.f;
            #pragma unroll
            for (int jj = 0; jj < 4; ++jj) {
                pa = fmaf(f8tof((k8a.x >> (8 * jj)) & 0xff), qv[jj], pa);
                pa = fmaf(f8tof((k8a.y >> (8 * jj)) & 0xff), qv[4 + jj], pa);
            }
            pa += __shfl_xor(pa, 1, 64);
            pa += __shfl_xor(pa, 2, 64);
            const float exa = __expf(pa * scale);
            den += exa;
            #pragma unroll
            for (int jj = 0; jj < 8; ++jj) acc[jj] = fmaf(bfe(v8a, jj), exa, acc[jj]);
        }
    }

    // epilogue — group-local
    const float inv = 1.f / (den + 1e-16f);
    float o[8], sk[8];
    {
        const ushort8v s8 = *(const ushort8v*)&sk_l[r][ch];
        #pragma unroll
        for (int j = 0; j < 8; ++j) sk[j] = bfe(s8, j);
    }
    float part = 0.f;
    #pragma unroll
    for (int j = 0; j < 8; ++j) {
        o[j] = acc[j] * inv;
        part += o[j] * Wbeta[ch + j] + sk[j] * Wbeta[HC + ch + j]
              + (o[j] - sk[j]) * Wbeta[2 * HC + ch + j];
    }
    part += __shfl_xor(part, 1, 64);
    part += __shfl_xor(part, 2, 64);
    part += __shfl_xor(part, 4, 64);
    part += __shfl_xor(part, 8, 64);

    const float beta = 1.f / (1.f + __expf(-part));
    if (nok) {
        union { unsigned short h[8]; ushort8v v8; } pk;
        #pragma unroll
        for (int j = 0; j < 8; ++j) {
            float rv = beta * sk[j] + (1.f - beta) * o[j];
            rv = (rv >= 0.f) ? rv : 0.01f * rv;
            pk.h[j] = f2bf(rv);
        }
        *(ushort8v*)(gout + (size_t)n * HC + ch) = pk.v8;
    }
}

// ---------------- fused pool + final GEMM (4 graphs per block) ----------------
__global__ __launch_bounds__(256) void pool_final(
    const __hip_bfloat16* __restrict__ gout, const int* __restrict__ batch,
    const float* __restrict__ W2, const float* __restrict__ b2,
    float* __restrict__ out, int N, int G)
{
    const int g0 = blockIdx.x * 4;
    __shared__ float p[4][HC];
    const int wave = threadIdx.x >> 6;
    const int lane = threadIdx.x & 63;
    const int g = g0 + wave;
    if (g < G) {
        int lo = 0, hi = N;
        while (lo < hi) { const int m = (lo + hi) >> 1; if (batch[m] < g) lo = m + 1; else hi = m; }
        int lo2 = lo, hi2 = N;
        while (lo2 < hi2) { const int m = (lo2 + hi2) >> 1; if (batch[m] < g + 1) lo2 = m + 1; else hi2 = m; }
        float a0 = 0.f, a1 = 0.f;
        for (int r = lo; r < lo2; ++r) {
            const __hip_bfloat162 g2 = *(const __hip_bfloat162*)(gout + (size_t)r * HC + 2 * lane);
            a0 += __bfloat162float(g2.x);
            a1 += __bfloat162float(g2.y);
        }
        const float invc = 1.f / fmaxf((float)(lo2 - lo), 1.f);
        p[wave][2 * lane]     = a0 * invc;
        p[wave][2 * lane + 1] = a1 * invc;
    }
    __syncthreads();
    const int t = threadIdx.x;
    for (int j = t; j < NOUT; j += 256) {
        const float bj = b2[j];
        float a0 = bj, a1 = bj, a2 = bj, a3 = bj;
        #pragma unroll 4
        for (int c = 0; c < HC; ++c) {
            const float w = W2[(size_t)c * NOUT + j];
            a0 = fmaf(p[0][c], w, a0);
            a1 = fmaf(p[1][c], w, a1);
            a2 = fmaf(p[2][c], w, a2);
            a3 = fmaf(p[3][c], w, a3);
        }
        if (g0     < G) out[(size_t)(g0    ) * NOUT + j] = a0;
        if (g0 + 1 < G) out[(size_t)(g0 + 1) * NOUT + j] = a1;
        if (g0 + 2 < G) out[(size_t)(g0 + 2) * NOUT + j] = a2;
        if (g0 + 3 < G) out[(size_t)(g0 + 3) * NOUT + j] = a3;
    }
}

// ---------------- launch ----------------
extern "C" void kernel_launch(void* const* d_in, const int* in_sizes, int n_in,
                              void* d_out, int out_size, void* d_ws, size_t ws_size,
                              hipStream_t stream) {
    const float* x     = (const float*)d_in[0];
    const int*   ei    = (const int*)d_in[1];
    const int*   batch = (const int*)d_in[2];
    const float* Wq  = (const float*)d_in[3];  const float* bq  = (const float*)d_in[4];
    const float* Wk  = (const float*)d_in[5];  const float* bk  = (const float*)d_in[6];
    const float* Wv  = (const float*)d_in[7];  const float* bv  = (const float*)d_in[8];
    const float* Wsk = (const float*)d_in[9];  const float* bsk = (const float*)d_in[10];
    const float* Wbeta = (const float*)d_in[11];
    const float* W2  = (const float*)d_in[12]; const float* b2  = (const float*)d_in[13];

    const int N = in_sizes[0] / NIN;
    const int E = in_sizes[1] / 2;
    const int G = out_size / NOUT;

    char* ws = (char*)d_ws;
    unsigned char* kvb = (unsigned char*)ws;                  // N x 384 B
    char* p0 = ws + (size_t)N * KVSTRIDE;
    unsigned short* Wtb = (unsigned short*)p0;            p0 += 4 * 128 * 128 * sizeof(unsigned short);
    int* cnt    = (int*)p0;                               p0 += (size_t)N * sizeof(int);
    int* start  = (int*)p0;                               p0 += (size_t)N * sizeof(int);
    int* cursor = (int*)p0;                               p0 += (size_t)N * sizeof(int);
    int* bsum   = (int*)p0;                               p0 += 1024 * sizeof(int);
    int* bpref  = (int*)p0;                               p0 += 1024 * sizeof(int);
    int* csr    = (int*)p0;                               p0 += (size_t)E * sizeof(int);
    __hip_bfloat16* gout = (__hip_bfloat16*)p0;

    hipMemsetAsync(cnt, 0, (size_t)N * sizeof(int), stream);

    const int eb = (E + 255) / 256;
    const int NB = (N + 1023) / 1024;
    const int nGemm = (N + 127) / 128;

    prep_hist<<<4 + eb, 256, 0, stream>>>(Wq, Wk, Wv, Wsk, Wtb, ei, cnt, E);
    scan_part<<<NB, 1024, 0, stream>>>(cnt, start, cursor, bsum, N);
    bpref_scan<<<1, 128, 0, stream>>>(bsum, bpref, NB);
    gemm_scatter<<<nGemm + eb, 256, 0, stream>>>(x, Wtb, bk, bv, kvb, N,
                                                 ei, cursor, bpref, csr, E, nGemm);

    node_aggr_fused<<<(N + 15) / 16, 256, 0, stream>>>(x, Wtb, bq, bsk, kvb,
                                                       start, cnt, bpref, csr,
                                                       Wbeta, gout, N);

    pool_final<<<(G + 3) / 4, 256, 0, stream>>>(gout, batch, W2, b2,
                                                (float*)d_out, N, G);
}

// Round 19
// 261.961 us; speedup vs baseline: 1.0891x; 1.0008x over previous
//
#include <hip/hip_runtime.h>
#include <hip/hip_bf16.h>
#include <hip/hip_fp8.h>
#include <math.h>

#define NIN 128
#define HC 128
#define NOUT 768
#define KVSTRIDE 384   // bytes per kv row: 128 B fp8 k | 256 B bf16 v

typedef __attribute__((ext_vector_type(8))) short bf16x8;
typedef __attribute__((ext_vector_type(4))) float f32x4;
typedef __attribute__((ext_vector_type(4))) unsigned short ushort4v;
typedef __attribute__((ext_vector_type(8))) unsigned short ushort8v;

__device__ __forceinline__ unsigned short f2bf(float f) {
    __hip_bfloat16 h = __float2bfloat16(f);
    return *(unsigned short*)&h;
}

__device__ __forceinline__ float bfe(ushort8v u, int j) {
    return __uint_as_float(((unsigned int)u[j]) << 16);
}

__device__ __forceinline__ float f8tof(unsigned char b) {
    __hip_fp8_e4m3 h; h.__x = b; return (float)h;
}
__device__ __forceinline__ unsigned char ftof8(float f) {
    __hip_fp8_e4m3 h(f); return h.__x;
}

// ---------------- Dispatch 1: prep_w (blocks 0..3) + hist (blocks 4..) ----------------
__global__ __launch_bounds__(256) void prep_hist(
    const float* __restrict__ Wq, const float* __restrict__ Wk,
    const float* __restrict__ Wv, const float* __restrict__ Wsk,
    unsigned short* __restrict__ Wtb,
    const int* __restrict__ ei, int* __restrict__ cnt, int E)
{
    if (blockIdx.x < 4) {
        const float* W = (blockIdx.x == 0) ? Wq : (blockIdx.x == 1) ? Wk
                       : (blockIdx.x == 2) ? Wv : Wsk;
        unsigned short* out = Wtb + (size_t)blockIdx.x * 128 * 128;
        const int t = threadIdx.x;
        for (int s = 0; s < 16; ++s) {
            const int f = t + s * 256;
            const int k = f >> 5;
            const int n = (f & 31) * 4;
            float4 w4 = *(const float4*)(W + (size_t)k * 128 + n);
            out[(size_t)(n    ) * 128 + k] = f2bf(w4.x);
            out[(size_t)(n + 1) * 128 + k] = f2bf(w4.y);
            out[(size_t)(n + 2) * 128 + k] = f2bf(w4.z);
            out[(size_t)(n + 3) * 128 + k] = f2bf(w4.w);
        }
    } else {
        const int e = (blockIdx.x - 4) * 256 + threadIdx.x;
        if (e < E) atomicAdd(cnt + ei[E + e], 1);
    }
}

// ---------------- scan: per-1024-chunk local exclusive offsets ----------------
__global__ __launch_bounds__(1024) void scan_part(
    const int* __restrict__ cnt, int* __restrict__ start,
    int* __restrict__ cursor, int* __restrict__ bsum, int N)
{
    __shared__ int wsum[16];
    const int tid = threadIdx.x;
    const int lane = tid & 63;
    const int w = tid >> 6;
    const int i = blockIdx.x * 1024 + tid;
    const int v = (i < N) ? cnt[i] : 0;
    int xv = v;
    #pragma unroll
    for (int off = 1; off < 64; off <<= 1) {
        const int y = __shfl_up(xv, off, 64);
        if (lane >= off) xv += y;
    }
    if (lane == 63) wsum[w] = xv;
    __syncthreads();
    if (tid < 16) {
        int y = wsum[tid];
        #pragma unroll
        for (int off = 1; off < 16; off <<= 1) {
            const int z = __shfl_up(y, off, 64);
            if (tid >= off) y += z;
        }
        wsum[tid] = y;
    }
    __syncthreads();
    const int excl = (w > 0 ? wsum[w - 1] : 0) + xv - v;
    if (i < N) { start[i] = excl; cursor[i] = excl; }
    if (tid == 1023) bsum[blockIdx.x] = wsum[15];
}

// 1-block exclusive scan of chunk totals (NB <= 128)
__global__ __launch_bounds__(128) void bpref_scan(
    const int* __restrict__ bsum, int* __restrict__ bpref, int NB)
{
    const int tid = threadIdx.x;
    __shared__ int w0tot;
    const int v = (tid < NB) ? bsum[tid] : 0;
    int xv = v;
    const int lane = tid & 63;
    #pragma unroll
    for (int off = 1; off < 64; off <<= 1) {
        const int y = __shfl_up(xv, off, 64);
        if (lane >= off) xv += y;
    }
    if (tid == 63) w0tot = xv;
    __syncthreads();
    const int incl = xv + ((tid >= 64) ? w0tot : 0);
    if (tid < NB) bpref[tid] = incl - v;
}

// ---------------- Dispatch 4: gemm_kv (blocks 0..nG-1) + scatter (rest) ----------------
__global__ __launch_bounds__(256, 4) void gemm_scatter(
    const float* __restrict__ x, const unsigned short* __restrict__ Wtb,
    const float* __restrict__ bk, const float* __restrict__ bv,
    unsigned char* __restrict__ kvb, int N,
    const int* __restrict__ ei, int* __restrict__ cursor,
    const int* __restrict__ bpref, int* __restrict__ csr_src, int E, int nGemm)
{
    __shared__ unsigned short At[128][136];

    if ((int)blockIdx.x >= nGemm) {
        const int e = (blockIdx.x - nGemm) * 256 + threadIdx.x;
        if (e < E) {
            const int d = ei[E + e];
            const int pos = bpref[d >> 10] + atomicAdd(cursor + d, 1);
            __builtin_nontemporal_store(ei[e], csr_src + pos);   // no line allocate
        }
        return;
    }

    const int tid = threadIdx.x;
    const int lane = tid & 63;
    const int wave = tid >> 6;
    const int rowBase = blockIdx.x * 128;
    const bool full = (rowBase + 128 <= N);

    #pragma unroll
    for (int s = 0; s < 16; ++s) {
        const int f = tid + s * 256;
        const int r = f >> 5;
        const int cl = (f & 31) * 4;
        const int gr = rowBase + r;
        float4 a4 = make_float4(0.f, 0.f, 0.f, 0.f);
        if (full || gr < N) a4 = *(const float4*)(x + (size_t)gr * 128 + cl);
        ushort4v u;
        u.x = f2bf(a4.x); u.y = f2bf(a4.y); u.z = f2bf(a4.z); u.w = f2bf(a4.w);
        *(ushort4v*)&At[r][cl] = u;
    }
    __syncthreads();

    bf16x8 afr[2][4];
    #pragma unroll
    for (int m = 0; m < 2; ++m)
        #pragma unroll
        for (int kk = 0; kk < 4; ++kk)
            afr[m][kk] = *(bf16x8*)&At[wave * 32 + m * 16 + (lane & 15)]
                                    [kk * 32 + (lane >> 4) * 8];

    const int colb = lane & 15;
    const int kofs = (lane >> 4) * 8;
    const int g4   = (lane >> 4) * 4;

    #pragma unroll
    for (int w2 = 0; w2 < 2; ++w2) {
        const unsigned short* Wp = Wtb + (size_t)(1 + w2) * 128 * 128;  // Wk, Wv
        const float* bias = (w2 == 0) ? bk : bv;

        f32x4 acc[2][8];
        #pragma unroll
        for (int m = 0; m < 2; ++m)
            #pragma unroll
            for (int nr = 0; nr < 8; ++nr)
                acc[m][nr] = (f32x4){0.f, 0.f, 0.f, 0.f};

        #pragma unroll
        for (int nr = 0; nr < 8; ++nr) {
            bf16x8 bfr[4];
            #pragma unroll
            for (int kk = 0; kk < 4; ++kk)
                bfr[kk] = *(const bf16x8*)(Wp + (size_t)(nr * 16 + colb) * 128
                                               + kk * 32 + kofs);
            #pragma unroll
            for (int kk = 0; kk < 4; ++kk) {
                #pragma unroll
                for (int m = 0; m < 2; ++m)
                    acc[m][nr] = __builtin_amdgcn_mfma_f32_16x16x32_bf16(
                        bfr[kk], afr[m][kk], acc[m][nr], 0, 0, 0);   // swapped
            }
        }

        #pragma unroll
        for (int m = 0; m < 2; ++m) {
            const int xrow = rowBase + wave * 32 + m * 16 + (lane & 15);
            if (full || xrow < N) {
                unsigned char* row = kvb + (size_t)xrow * KVSTRIDE;
                #pragma unroll
                for (int nr = 0; nr < 8; ++nr) {
                    const int colb4 = nr * 16 + g4;
                    const float4 b4 = *(const float4*)(bias + colb4);
                    if (w2 == 0) {   // k -> fp8, 4 B per lane
                        unsigned int p = (unsigned int)ftof8(acc[m][nr][0] + b4.x)
                                       | ((unsigned int)ftof8(acc[m][nr][1] + b4.y) << 8)
                                       | ((unsigned int)ftof8(acc[m][nr][2] + b4.z) << 16)
                                       | ((unsigned int)ftof8(acc[m][nr][3] + b4.w) << 24);
                        *(unsigned int*)(row + colb4) = p;
                    } else {         // v -> bf16, 8 B per lane
                        ushort4v pk;
                        pk.x = f2bf(acc[m][nr][0] + b4.x);
                        pk.y = f2bf(acc[m][nr][1] + b4.y);
                        pk.z = f2bf(acc[m][nr][2] + b4.z);
                        pk.w = f2bf(acc[m][nr][3] + b4.w);
                        *(ushort4v*)(row + 128 + 2 * colb4) = pk;
                    }
                }
            }
        }
    }
}

// ---------------- Kernel B: fused q/skip-MFMA + attention + gate (R14 form) ----------------
__global__ __launch_bounds__(256) void node_aggr_fused(
    const float* __restrict__ x, const unsigned short* __restrict__ Wtb,
    const float* __restrict__ bq, const float* __restrict__ bsk,
    const unsigned char* __restrict__ kvb,
    const int* __restrict__ start, const int* __restrict__ cnt,
    const int* __restrict__ bpref,
    const int* __restrict__ csr_src, const float* __restrict__ Wbeta,
    __hip_bfloat16* __restrict__ gout, int N)
{
    __shared__ unsigned short At[16][136];
    __shared__ unsigned short q_l[16][136];
    __shared__ unsigned short sk_l[16][136];

    const int tid = threadIdx.x;
    const int lane = tid & 63;
    const int wave = tid >> 6;
    const int n0 = blockIdx.x * 16;

    const int g  = lane >> 4;
    const int t  = lane & 15;
    const int ch = t * 8;
    const int r  = wave * 4 + g;
    const int n  = n0 + r;
    const bool nok = (n < N);
    int s0v = 0, cntv = 0;
    if (nok) { s0v = start[n] + bpref[n >> 10]; cntv = cnt[n]; }

    #pragma unroll
    for (int s = 0; s < 2; ++s) {
        const int f = tid + s * 256;
        const int rr = f >> 5;
        const int cl = (f & 31) * 4;
        const int gr = n0 + rr;
        float4 a4 = make_float4(0.f, 0.f, 0.f, 0.f);
        if (gr < N) a4 = *(const float4*)(x + (size_t)gr * 128 + cl);
        ushort4v u;
        u.x = f2bf(a4.x); u.y = f2bf(a4.y); u.z = f2bf(a4.z); u.w = f2bf(a4.w);
        *(ushort4v*)&At[rr][cl] = u;
    }
    __syncthreads();

    {
        bf16x8 afr[4];
        #pragma unroll
        for (int kk = 0; kk < 4; ++kk)
            afr[kk] = *(bf16x8*)&At[lane & 15][kk * 32 + (lane >> 4) * 8];
        const int colb = lane & 15;
        const int kofs = (lane >> 4) * 8;
        const int g4m  = (lane >> 4) * 4;
        const int rm   = lane & 15;

        f32x4 acc[2][2];
        #pragma unroll
        for (int a = 0; a < 2; ++a)
            #pragma unroll
            for (int b = 0; b < 2; ++b)
                acc[a][b] = (f32x4){0.f, 0.f, 0.f, 0.f};

        #pragma unroll
        for (int nr2 = 0; nr2 < 2; ++nr2) {
            const int nr = wave * 2 + nr2;
            #pragma unroll
            for (int wsel = 0; wsel < 2; ++wsel) {
                const unsigned short* Wp = Wtb + (size_t)(wsel == 0 ? 0 : 3) * 128 * 128;
                bf16x8 bfr[4];
                #pragma unroll
                for (int kk = 0; kk < 4; ++kk)
                    bfr[kk] = *(const bf16x8*)(Wp + (size_t)(nr * 16 + colb) * 128
                                                   + kk * 32 + kofs);
                #pragma unroll
                for (int kk = 0; kk < 4; ++kk)
                    acc[wsel][nr2] = __builtin_amdgcn_mfma_f32_16x16x32_bf16(
                        bfr[kk], afr[kk], acc[wsel][nr2], 0, 0, 0);
            }
        }

        #pragma unroll
        for (int nr2 = 0; nr2 < 2; ++nr2) {
            const int col = (wave * 2 + nr2) * 16 + g4m;
            ushort4v qp, sp;
            #pragma unroll
            for (int j = 0; j < 4; ++j) {
                qp[j] = f2bf(acc[0][nr2][j] + bq[col + j]);
                sp[j] = f2bf(acc[1][nr2][j] + bsk[col + j]);
            }
            *(ushort4v*)&q_l[rm][col]  = qp;
            *(ushort4v*)&sk_l[rm][col] = sp;
        }
    }
    __syncthreads();

    // ---- phase 2: group-per-node, 2-edge pipeline, kv row [fp8 k | bf16 v] ----
    const float scale = 0.17677669529663687f;   // 1/sqrt(32)

    float qv[8];
    {
        const ushort8v q8 = *(const ushort8v*)&q_l[r][ch];
        #pragma unroll
        for (int j = 0; j < 8; ++j) qv[j] = bfe(q8, j);
    }

    const int e1v = s0v + cntv;
    float den = 0.f;
    float acc[8];
    #pragma unroll
    for (int j = 0; j < 8; ++j) acc[j] = 0.f;

    for (int base = s0v; base < e1v; base += 16) {
        const int nblk = min(16, e1v - base);
        const int sidx = csr_src[base + min(t, nblk - 1)];
        int j = 0;
        for (; j + 1 < nblk; j += 2) {
            const int sa = __shfl(sidx, g * 16 + j,     64);
            const int sb = __shfl(sidx, g * 16 + j + 1, 64);
            const unsigned char* rowa = kvb + (size_t)sa * KVSTRIDE;
            const unsigned char* rowb = kvb + (size_t)sb * KVSTRIDE;
            const uint2 k8a = *(const uint2*)(rowa + ch);          // 8 fp8
            const ushort8v v8a = *(const ushort8v*)(rowa + 128 + 2 * ch);
            const uint2 k8b = *(const uint2*)(rowb + ch);
            const ushort8v v8b = *(const ushort8v*)(rowb + 128 + 2 * ch);
            float pa = 0.f, pb = 0.f;
            #pragma unroll
            for (int jj = 0; jj < 4; ++jj) {
                pa = fmaf(f8tof((k8a.x >> (8 * jj)) & 0xff), qv[jj], pa);
                pa = fmaf(f8tof((k8a.y >> (8 * jj)) & 0xff), qv[4 + jj], pa);
                pb = fmaf(f8tof((k8b.x >> (8 * jj)) & 0xff), qv[jj], pb);
                pb = fmaf(f8tof((k8b.y >> (8 * jj)) & 0xff), qv[4 + jj], pb);
            }
            pa += __shfl_xor(pa, 1, 64);
            pa += __shfl_xor(pa, 2, 64);
            pb += __shfl_xor(pb, 1, 64);
            pb += __shfl_xor(pb, 2, 64);
            const float exa = __expf(pa * scale);
            const float exb = __expf(pb * scale);
            den += exa + exb;
            #pragma unroll
            for (int jj = 0; jj < 8; ++jj)
                acc[jj] = fmaf(bfe(v8a, jj), exa, fmaf(bfe(v8b, jj), exb, acc[jj]));
        }
        if (j < nblk) {
            const int sa = __shfl(sidx, g * 16 + j, 64);
            const unsigned char* rowa = kvb + (size_t)sa * KVSTRIDE;
            const uint2 k8a = *(const uint2*)(rowa + ch);
            const ushort8v v8a = *(const ushort8v*)(rowa + 128 + 2 * ch);
            float pa = 0.f;
            #pragma unroll
            for (int jj = 0; jj < 4; ++jj) {
                pa = fmaf(f8tof((k8a.x >> (8 * jj)) & 0xff), qv[jj], pa);
                pa = fmaf(f8tof((k8a.y >> (8 * jj)) & 0xff), qv[4 + jj], pa);
            }
            pa += __shfl_xor(pa, 1, 64);
            pa += __shfl_xor(pa, 2, 64);
            const float exa = __expf(pa * scale);
            den += exa;
            #pragma unroll
            for (int jj = 0; jj < 8; ++jj) acc[jj] = fmaf(bfe(v8a, jj), exa, acc[jj]);
        }
    }

    // epilogue — group-local
    const float inv = 1.f / (den + 1e-16f);
    float o[8], sk[8];
    {
        const ushort8v s8 = *(const ushort8v*)&sk_l[r][ch];
        #pragma unroll
        for (int j = 0; j < 8; ++j) sk[j] = bfe(s8, j);
    }
    float part = 0.f;
    #pragma unroll
    for (int j = 0; j < 8; ++j) {
        o[j] = acc[j] * inv;
        part += o[j] * Wbeta[ch + j] + sk[j] * Wbeta[HC + ch + j]
              + (o[j] - sk[j]) * Wbeta[2 * HC + ch + j];
    }
    part += __shfl_xor(part, 1, 64);
    part += __shfl_xor(part, 2, 64);
    part += __shfl_xor(part, 4, 64);
    part += __shfl_xor(part, 8, 64);

    const float beta = 1.f / (1.f + __expf(-part));
    if (nok) {
        union { unsigned short h[8]; ushort8v v8; } pk;
        #pragma unroll
        for (int j = 0; j < 8; ++j) {
            float rv = beta * sk[j] + (1.f - beta) * o[j];
            rv = (rv >= 0.f) ? rv : 0.01f * rv;
            pk.h[j] = f2bf(rv);
        }
        *(ushort8v*)(gout + (size_t)n * HC + ch) = pk.v8;
    }
}

// ---------------- fused pool + final GEMM (4 graphs per block) ----------------
__global__ __launch_bounds__(256) void pool_final(
    const __hip_bfloat16* __restrict__ gout, const int* __restrict__ batch,
    const float* __restrict__ W2, const float* __restrict__ b2,
    float* __restrict__ out, int N, int G)
{
    const int g0 = blockIdx.x * 4;
    __shared__ float p[4][HC];
    const int wave = threadIdx.x >> 6;
    const int lane = threadIdx.x & 63;
    const int g = g0 + wave;
    if (g < G) {
        int lo = 0, hi = N;
        while (lo < hi) { const int m = (lo + hi) >> 1; if (batch[m] < g) lo = m + 1; else hi = m; }
        int lo2 = lo, hi2 = N;
        while (lo2 < hi2) { const int m = (lo2 + hi2) >> 1; if (batch[m] < g + 1) lo2 = m + 1; else hi2 = m; }
        float a0 = 0.f, a1 = 0.f;
        for (int r = lo; r < lo2; ++r) {
            const __hip_bfloat162 g2 = *(const __hip_bfloat162*)(gout + (size_t)r * HC + 2 * lane);
            a0 += __bfloat162float(g2.x);
            a1 += __bfloat162float(g2.y);
        }
        const float invc = 1.f / fmaxf((float)(lo2 - lo), 1.f);
        p[wave][2 * lane]     = a0 * invc;
        p[wave][2 * lane + 1] = a1 * invc;
    }
    __syncthreads();
    const int t = threadIdx.x;
    for (int j = t; j < NOUT; j += 256) {
        const float bj = b2[j];
        float a0 = bj, a1 = bj, a2 = bj, a3 = bj;
        #pragma unroll 4
        for (int c = 0; c < HC; ++c) {
            const float w = W2[(size_t)c * NOUT + j];
            a0 = fmaf(p[0][c], w, a0);
            a1 = fmaf(p[1][c], w, a1);
            a2 = fmaf(p[2][c], w, a2);
            a3 = fmaf(p[3][c], w, a3);
        }
        if (g0     < G) out[(size_t)(g0    ) * NOUT + j] = a0;
        if (g0 + 1 < G) out[(size_t)(g0 + 1) * NOUT + j] = a1;
        if (g0 + 2 < G) out[(size_t)(g0 + 2) * NOUT + j] = a2;
        if (g0 + 3 < G) out[(size_t)(g0 + 3) * NOUT + j] = a3;
    }
}

// ---------------- launch ----------------
extern "C" void kernel_launch(void* const* d_in, const int* in_sizes, int n_in,
                              void* d_out, int out_size, void* d_ws, size_t ws_size,
                              hipStream_t stream) {
    const float* x     = (const float*)d_in[0];
    const int*   ei    = (const int*)d_in[1];
    const int*   batch = (const int*)d_in[2];
    const float* Wq  = (const float*)d_in[3];  const float* bq  = (const float*)d_in[4];
    const float* Wk  = (const float*)d_in[5];  const float* bk  = (const float*)d_in[6];
    const float* Wv  = (const float*)d_in[7];  const float* bv  = (const float*)d_in[8];
    const float* Wsk = (const float*)d_in[9];  const float* bsk = (const float*)d_in[10];
    const float* Wbeta = (const float*)d_in[11];
    const float* W2  = (const float*)d_in[12]; const float* b2  = (const float*)d_in[13];

    const int N = in_sizes[0] / NIN;
    const int E = in_sizes[1] / 2;
    const int G = out_size / NOUT;

    char* ws = (char*)d_ws;
    unsigned char* kvb = (unsigned char*)ws;                  // N x 384 B
    char* p0 = ws + (size_t)N * KVSTRIDE;
    unsigned short* Wtb = (unsigned short*)p0;            p0 += 4 * 128 * 128 * sizeof(unsigned short);
    int* cnt    = (int*)p0;                               p0 += (size_t)N * sizeof(int);
    int* start  = (int*)p0;                               p0 += (size_t)N * sizeof(int);
    int* cursor = (int*)p0;                               p0 += (size_t)N * sizeof(int);
    int* bsum   = (int*)p0;                               p0 += 1024 * sizeof(int);
    int* bpref  = (int*)p0;                               p0 += 1024 * sizeof(int);
    int* csr    = (int*)p0;                               p0 += (size_t)E * sizeof(int);
    __hip_bfloat16* gout = (__hip_bfloat16*)p0;

    hipMemsetAsync(cnt, 0, (size_t)N * sizeof(int), stream);

    const int eb = (E + 255) / 256;
    const int NB = (N + 1023) / 1024;
    const int nGemm = (N + 127) / 128;

    prep_hist<<<4 + eb, 256, 0, stream>>>(Wq, Wk, Wv, Wsk, Wtb, ei, cnt, E);
    scan_part<<<NB, 1024, 0, stream>>>(cnt, start, cursor, bsum, N);
    bpref_scan<<<1, 128, 0, stream>>>(bsum, bpref, NB);
    gemm_scatter<<<nGemm + eb, 256, 0, stream>>>(x, Wtb, bk, bv, kvb, N,
                                                 ei, cursor, bpref, csr, E, nGemm);

    node_aggr_fused<<<(N + 15) / 16, 256, 0, stream>>>(x, Wtb, bq, bsk, kvb,
                                                       start, cnt, bpref, csr,
                                                       Wbeta, gout, N);

    pool_final<<<(G + 3) / 4, 256, 0, stream>>>(gout, batch, W2, b2,
                                                (float*)d_out, N, G);
}